// Round 1
// baseline (1772.711 us; speedup 1.0000x reference)
//
#include <hip/hip_runtime.h>
#include <math.h>

// Problem constants
#define BGR   256
#define NPG1  1024
#define NEDGE 4194304
#define NTOT  262144
#define KK1   512
#define KK2   256
#define KK3   128
#define NK1   131072
#define NK2   65536
#define FDIM  128

// ---------------------------------------------------------------------------
// GEMM: C = (relu)(A @ W + b), A[M,128] row-major, W[128,128] row-major (in,out)
// Block: 128 threads, tile 64 rows x 128 cols, BK=32.
// ---------------------------------------------------------------------------
__global__ __launch_bounds__(128) void gemm128(
    const float* __restrict__ A, const float* __restrict__ W,
    const float* __restrict__ bias, float* __restrict__ C, int doRelu)
{
    __shared__ float As[64 * 33];    // [row][kk], stride 33 (pad) -> 2-way max
    __shared__ float Ws[32 * 132];   // [kk][col], stride 132 (16B aligned)
    int t  = threadIdx.x;
    int tr = t & 7;    // row group: rows tr*8 .. tr*8+7
    int tc = t >> 3;   // col group: cols tc*4..+3 and 64+tc*4..+3
    size_t rowBase = (size_t)blockIdx.x * 64;
    int cA = tc * 4, cB = 64 + tc * 4;

    float acc[8][8];
#pragma unroll
    for (int i = 0; i < 8; i++)
#pragma unroll
        for (int j = 0; j < 8; j++) acc[i][j] = 0.f;

    for (int kk0 = 0; kk0 < 128; kk0 += 32) {
        // stage A tile: 64 rows x 32 k  (512 float4 loads)
#pragma unroll
        for (int q = t; q < 512; q += 128) {
            int row = q >> 3, kg = q & 7;
            float4 av = *(const float4*)(A + (rowBase + row) * 128 + kk0 + kg * 4);
            float* p = &As[row * 33 + kg * 4];
            p[0] = av.x; p[1] = av.y; p[2] = av.z; p[3] = av.w;
        }
        // stage W tile: 32 k x 128 cols (1024 float4)
#pragma unroll
        for (int q = t; q < 1024; q += 128) {
            int kk = q >> 5, c4 = q & 31;
            *(float4*)(&Ws[kk * 132 + c4 * 4]) =
                *(const float4*)(W + (size_t)(kk0 + kk) * 128 + c4 * 4);
        }
        __syncthreads();
#pragma unroll 8
        for (int kk = 0; kk < 32; kk++) {
            float4 b0 = *(const float4*)(&Ws[kk * 132 + cA]);
            float4 b1 = *(const float4*)(&Ws[kk * 132 + cB]);
            float a[8];
#pragma unroll
            for (int i = 0; i < 8; i++) a[i] = As[(tr * 8 + i) * 33 + kk];
#pragma unroll
            for (int i = 0; i < 8; i++) {
                acc[i][0] = fmaf(a[i], b0.x, acc[i][0]);
                acc[i][1] = fmaf(a[i], b0.y, acc[i][1]);
                acc[i][2] = fmaf(a[i], b0.z, acc[i][2]);
                acc[i][3] = fmaf(a[i], b0.w, acc[i][3]);
                acc[i][4] = fmaf(a[i], b1.x, acc[i][4]);
                acc[i][5] = fmaf(a[i], b1.y, acc[i][5]);
                acc[i][6] = fmaf(a[i], b1.z, acc[i][6]);
                acc[i][7] = fmaf(a[i], b1.w, acc[i][7]);
            }
        }
        __syncthreads();
    }
    float bv[8] = {bias[cA], bias[cA+1], bias[cA+2], bias[cA+3],
                   bias[cB], bias[cB+1], bias[cB+2], bias[cB+3]};
#pragma unroll
    for (int i = 0; i < 8; i++) {
        size_t r = rowBase + tr * 8 + i;
        float4 o0, o1;
        o0.x = acc[i][0] + bv[0]; o0.y = acc[i][1] + bv[1];
        o0.z = acc[i][2] + bv[2]; o0.w = acc[i][3] + bv[3];
        o1.x = acc[i][4] + bv[4]; o1.y = acc[i][5] + bv[5];
        o1.z = acc[i][6] + bv[6]; o1.w = acc[i][7] + bv[7];
        if (doRelu) {
            o0.x = fmaxf(o0.x, 0.f); o0.y = fmaxf(o0.y, 0.f);
            o0.z = fmaxf(o0.z, 0.f); o0.w = fmaxf(o0.w, 0.f);
            o1.x = fmaxf(o1.x, 0.f); o1.y = fmaxf(o1.y, 0.f);
            o1.z = fmaxf(o1.z, 0.f); o1.w = fmaxf(o1.w, 0.f);
        }
        *(float4*)(C + r * 128 + cA) = o0;
        *(float4*)(C + r * 128 + cB) = o1;
    }
}

// ---------------------------------------------------------------------------
// hs[i] = dot(X[i,:], w[0:128])   (score GEMV, one wave per node)
// ---------------------------------------------------------------------------
__global__ void gemv_score(const float* __restrict__ X, const float* __restrict__ w,
                           float* __restrict__ hs, int M)
{
    __shared__ float ws[128];
    int t = threadIdx.x;
    if (t < 128) ws[t] = w[t];
    __syncthreads();
    int lane = t & 63, wid = t >> 6;
    int node = blockIdx.x * 4 + wid;
    if (node >= M) return;
    float2 xv = *(const float2*)(X + (size_t)node * 128 + lane * 2);
    float p = xv.x * ws[lane * 2] + xv.y * ws[lane * 2 + 1];
#pragma unroll
    for (int off = 32; off > 0; off >>= 1) p += __shfl_xor(p, off, 64);
    if (lane == 0) hs[node] = p;
}

// deg[dst] += 1 for active edges (lvl1: all active; else src>=0)
__global__ void edge_deg(const int* __restrict__ src, const int* __restrict__ dst,
                         float* __restrict__ deg, int lvl1)
{
    int e = blockIdx.x * 256 + threadIdx.x;
    if (e >= NEDGE) return;
    if (lvl1 || src[e] >= 0) atomicAdd(&deg[dst[e]], 1.0f);
}

// agg[dst] += dinv[src]*dinv[dst]*hs[src], dinv = 1/sqrt(deg+1)
__global__ void edge_agg(const int* __restrict__ src, const int* __restrict__ dst,
                         const float* __restrict__ deg, const float* __restrict__ hs,
                         float* __restrict__ agg)
{
    int e = blockIdx.x * 256 + threadIdx.x;
    if (e >= NEDGE) return;
    int s = src[e];
    if (s < 0) return;
    int d = dst[e];
    float ci = 1.0f / sqrtf(deg[s] + 1.0f);
    float cd = 1.0f / sqrtf(deg[d] + 1.0f);
    atomicAdd(&agg[d], ci * cd * hs[s]);
}

// s[i] = agg[i] + hs[i]/(deg[i]+1) + b;  written to two output slots
__global__ void score_fin(const float* __restrict__ agg, const float* __restrict__ hs,
                          const float* __restrict__ deg, const float* __restrict__ b,
                          float* __restrict__ o1, float* __restrict__ o2, int M)
{
    int i = blockIdx.x * 256 + threadIdx.x;
    if (i >= M) return;
    float s = agg[i] + hs[i] / (deg[i] + 1.0f) + b[0];
    o1[i] = s;
    o2[i] = s;
}

// ---------------------------------------------------------------------------
// Per-graph bitonic sort ascending by (score, idx). blockDim = npg/2.
// sidx[g*npg + i] = local index of i-th smallest.
// ---------------------------------------------------------------------------
__global__ void bitonic_sort(const float* __restrict__ score, int* __restrict__ sidx,
                             int npg)
{
    __shared__ float sk[1024];
    __shared__ int   sv[1024];
    int g = blockIdx.x, tid = threadIdx.x;
    const float* s = score + (size_t)g * npg;
    for (int i = tid; i < npg; i += blockDim.x) { sk[i] = s[i]; sv[i] = i; }
    __syncthreads();
    for (int size = 2; size <= npg; size <<= 1) {
        for (int stride = size >> 1; stride > 0; stride >>= 1) {
            int i = 2 * tid - (tid & (stride - 1));
            int j = i + stride;
            float ki = sk[i], kj = sk[j];
            int   vi = sv[i], vj = sv[j];
            bool up = ((i & size) == 0);
            bool gt = (ki > kj) || (ki == kj && vi > vj);
            if (gt == up) { sk[i] = kj; sk[j] = ki; sv[i] = vj; sv[j] = vi; }
            __syncthreads();
        }
    }
    for (int i = tid; i < npg; i += blockDim.x) sidx[(size_t)g * npg + i] = sv[i];
}

// xp[i,:] = feat[row,:] * tanh(score[row]), row = g*npg + sidx[g*npg + j]
__global__ void gather_gate(const float* __restrict__ feat, const float* __restrict__ score,
                            const int* __restrict__ sidx, float* __restrict__ outp,
                            int npg, int lgk, int NK)
{
    int tid = blockIdx.x * 256 + threadIdx.x;
    int i = tid >> 5, q = tid & 31;
    if (i >= NK) return;
    int g = i >> lgk, j = i & ((1 << lgk) - 1);
    int row = g * npg + sidx[g * npg + j];
    float gate = tanhf(score[row]);
    float4 v = *(const float4*)(feat + (size_t)row * 128 + q * 4);
    v.x *= gate; v.y *= gate; v.z *= gate; v.w *= gate;
    *(float4*)(outp + (size_t)i * 128 + q * 4) = v;
}

// out[g,f] += max_j v ; out[g,128+f] += mean_j v  (v = gated feature)
__global__ void readout(const float* __restrict__ feat, const float* __restrict__ score,
                        const int* __restrict__ sidx, float* __restrict__ outp,
                        int npg, int k, int base)
{
    int g = blockIdx.x, f = threadIdx.x;
    const int* sp = sidx + (size_t)g * npg + base;
    float mx = -INFINITY, sm = 0.f;
    for (int j = 0; j < k; j++) {
        int row = g * npg + sp[j];
        float v = feat[(size_t)row * 128 + f] * tanhf(score[row]);
        mx = fmaxf(mx, v);
        sm += v;
    }
    outp[g * 256 + f]       += mx;
    outp[g * 256 + 128 + f] += sm / (float)k;
}

// mp[g*npg + sidx[g*npg + j]] = g*k + j   (mp pre-set to -1)
__global__ void build_mp(const int* __restrict__ sidx, int* __restrict__ mp,
                         int npg, int lgk, int NK)
{
    int i = blockIdx.x * 256 + threadIdx.x;
    if (i >= NK) return;
    int g = i >> lgk, j = i & ((1 << lgk) - 1);
    mp[g * npg + sidx[g * npg + j]] = i;
}

// relabel edges; dropped edges get src = -1. Safe in-place.
__global__ void filter_edges(const int* __restrict__ srcIn, const int* __restrict__ dstIn,
                             const int* __restrict__ mp, int* __restrict__ srcOut,
                             int* __restrict__ dstOut)
{
    int e = blockIdx.x * 256 + threadIdx.x;
    if (e >= NEDGE) return;
    int s = srcIn[e];
    if (s < 0) { srcOut[e] = -1; dstOut[e] = 0; return; }
    int d = dstIn[e];
    int ms = mp[s], md = mp[d];
    bool keep = (ms >= 0) && (md >= 0);
    srcOut[e] = keep ? ms : -1;
    dstOut[e] = keep ? md : 0;
}

// MLP head: relu(x@Wl1+b) -> relu(@Wl2+b) -> log_softmax(@Wl3+b)
__global__ void head_kernel(const float* __restrict__ xr, const float* __restrict__ nr,
                            const float* __restrict__ Wl1, const float* __restrict__ bl1,
                            const float* __restrict__ Wl2, const float* __restrict__ bl2,
                            const float* __restrict__ Wl3, const float* __restrict__ bl3,
                            float* __restrict__ out0, float* __restrict__ out1)
{
    __shared__ float xv[256];
    __shared__ float v1[128];
    __shared__ float v2[64];
    __shared__ float lg[10];
    __shared__ float red[2];
    int row = blockIdx.x;
    const float* xs = blockIdx.y ? nr : xr;
    float* op = blockIdx.y ? out1 : out0;
    int t = threadIdx.x;
    xv[t] = xs[row * 256 + t];
    xv[t + 128] = xs[row * 256 + 128 + t];
    __syncthreads();
    float a = bl1[t];
    for (int i = 0; i < 256; i++) a = fmaf(xv[i], Wl1[i * 128 + t], a);
    v1[t] = fmaxf(a, 0.f);
    __syncthreads();
    if (t < 64) {
        float a2 = bl2[t];
        for (int i = 0; i < 128; i++) a2 = fmaf(v1[i], Wl2[i * 64 + t], a2);
        v2[t] = fmaxf(a2, 0.f);
    }
    __syncthreads();
    if (t < 10) {
        float a3 = bl3[t];
        for (int i = 0; i < 64; i++) a3 = fmaf(v2[i], Wl3[i * 10 + t], a3);
        lg[t] = a3;
    }
    __syncthreads();
    if (t == 0) {
        float m = -INFINITY;
        for (int c = 0; c < 10; c++) m = fmaxf(m, lg[c]);
        float se = 0.f;
        for (int c = 0; c < 10; c++) se += expf(lg[c] - m);
        red[0] = m; red[1] = logf(se);
    }
    __syncthreads();
    if (t < 10) op[row * 10 + t] = lg[t] - red[0] - red[1];
}

// ---------------------------------------------------------------------------
extern "C" void kernel_launch(void* const* d_in, const int* in_sizes, int n_in,
                              void* d_out, int out_size, void* d_ws, size_t ws_size,
                              hipStream_t stream)
{
    (void)in_sizes; (void)n_in; (void)out_size; (void)ws_size;
    const float* x    = (const float*)d_in[0];
    const int*   src0 = (const int*)d_in[1];
    const int*   dst0 = (const int*)d_in[2];
    const float* W1  = (const float*)d_in[4];  const float* b1  = (const float*)d_in[5];
    const float* W2  = (const float*)d_in[6];  const float* b2  = (const float*)d_in[7];
    const float* W3  = (const float*)d_in[8];  const float* b3  = (const float*)d_in[9];
    const float* Ws1 = (const float*)d_in[10]; const float* bs1 = (const float*)d_in[11];
    const float* Ws2 = (const float*)d_in[12]; const float* bs2 = (const float*)d_in[13];
    const float* Ws3 = (const float*)d_in[14]; const float* bs3 = (const float*)d_in[15];
    const float* Wl1 = (const float*)d_in[16]; const float* bl1 = (const float*)d_in[17];
    const float* Wl2 = (const float*)d_in[18]; const float* bl2 = (const float*)d_in[19];
    const float* Wl3 = (const float*)d_in[20]; const float* bl3 = (const float*)d_in[21];

    float* out = (float*)d_out;
    char*  ws  = (char*)d_ws;

    // workspace layout (bytes)
    float* h    = (float*)(ws + 0);             // 134217728, dead after level-1 readouts
    float* hp1  = (float*)(ws + 0);             // 67108864 (reuses h)
    float* hp2  = (float*)(ws + 67108864);      // 33554432 (reuses h)
    float* xp2  = (float*)(ws + 100663296);     // 33554432 (reuses h)
    float* xp1  = (float*)(ws + 134217728);     // 67108864
    int*   srcW = (int*)  (ws + 201326592);     // 16777216
    int*   dstW = (int*)  (ws + 218103808);     // 16777216
    int*   sidx = (int*)  (ws + 234881024);     // 1048576
    float* hs   = (float*)(ws + 235929600);     // 1048576
    float* deg  = (float*)(ws + 236978176);     // 1048576
    float* agg  = (float*)(ws + 238026752);     // 1048576
    int*   mp   = (int*)  (ws + 239075328);     // 1048576
    float* xr   = (float*)(ws + 240123904);     // 262144
    float* nr   = (float*)(ws + 240386048);     // 262144  (total 240648192 B)

    float* s1o  = out + 5120;   float* s1o2 = out + 267264;
    float* s2o  = out + 529408; float* s2o2 = out + 660480;
    float* s3o  = out + 791552; float* s3o2 = out + 857088;

    const int EBLK = NEDGE / 256; // 16384

    hipMemsetAsync(xr, 0, 524288, stream); // xr + nr

    // ---------------- Level 1 ----------------
    gemm128<<<NTOT / 64, 128, 0, stream>>>(x, W1, b1, h, 1);
    gemv_score<<<NTOT / 4, 256, 0, stream>>>(h, Ws1, hs, NTOT);
    hipMemsetAsync(deg, 0, 2097152, stream); // deg + agg
    edge_deg<<<EBLK, 256, 0, stream>>>(src0, dst0, deg, 1);
    edge_agg<<<EBLK, 256, 0, stream>>>(src0, dst0, deg, hs, agg);
    score_fin<<<NTOT / 256, 256, 0, stream>>>(agg, hs, deg, bs1, s1o, s1o2, NTOT);
    bitonic_sort<<<BGR, 512, 0, stream>>>(s1o, sidx, 1024);
    gather_gate<<<NK1 * 32 / 256, 256, 0, stream>>>(h, s1o, sidx, xp1, 1024, 9, NK1);
    readout<<<BGR, 128, 0, stream>>>(h, s1o, sidx, xr, 1024, 512, 0);
    readout<<<BGR, 128, 0, stream>>>(h, s1o, sidx, nr, 1024, 512, 512);
    hipMemsetAsync(mp, 0xFF, 1048576, stream);
    build_mp<<<NK1 / 256, 256, 0, stream>>>(sidx, mp, 1024, 9, NK1);
    filter_edges<<<EBLK, 256, 0, stream>>>(src0, dst0, mp, srcW, dstW);

    // ---------------- Level 2 ----------------
    gemm128<<<NK1 / 64, 128, 0, stream>>>(xp1, W2, b2, hp1, 1);
    gemv_score<<<NK1 / 4, 256, 0, stream>>>(hp1, Ws2, hs, NK1);
    hipMemsetAsync(deg, 0, 2097152, stream);
    edge_deg<<<EBLK, 256, 0, stream>>>(srcW, dstW, deg, 0);
    edge_agg<<<EBLK, 256, 0, stream>>>(srcW, dstW, deg, hs, agg);
    score_fin<<<NK1 / 256, 256, 0, stream>>>(agg, hs, deg, bs2, s2o, s2o2, NK1);
    bitonic_sort<<<BGR, 256, 0, stream>>>(s2o, sidx, 512);
    gather_gate<<<NK2 * 32 / 256, 256, 0, stream>>>(hp1, s2o, sidx, xp2, 512, 8, NK2);
    readout<<<BGR, 128, 0, stream>>>(hp1, s2o, sidx, xr, 512, 256, 0);
    readout<<<BGR, 128, 0, stream>>>(hp1, s2o, sidx, nr, 512, 256, 256);
    hipMemsetAsync(mp, 0xFF, 1048576, stream);
    build_mp<<<NK2 / 256, 256, 0, stream>>>(sidx, mp, 512, 8, NK2);
    filter_edges<<<EBLK, 256, 0, stream>>>(srcW, dstW, mp, srcW, dstW);

    // ---------------- Level 3 ----------------
    gemm128<<<NK2 / 64, 128, 0, stream>>>(xp2, W3, b3, hp2, 1);
    gemv_score<<<NK2 / 4, 256, 0, stream>>>(hp2, Ws3, hs, NK2);
    hipMemsetAsync(deg, 0, 2097152, stream);
    edge_deg<<<EBLK, 256, 0, stream>>>(srcW, dstW, deg, 0);
    edge_agg<<<EBLK, 256, 0, stream>>>(srcW, dstW, deg, hs, agg);
    score_fin<<<NK2 / 256, 256, 0, stream>>>(agg, hs, deg, bs3, s3o, s3o2, NK2);
    bitonic_sort<<<BGR, 128, 0, stream>>>(s3o, sidx, 256);
    readout<<<BGR, 128, 0, stream>>>(hp2, s3o, sidx, xr, 256, 128, 0);
    readout<<<BGR, 128, 0, stream>>>(hp2, s3o, sidx, nr, 256, 128, 128);

    // ---------------- Head ----------------
    head_kernel<<<dim3(BGR, 2), 128, 0, stream>>>(xr, nr, Wl1, bl1, Wl2, bl2,
                                                  Wl3, bl3, out, out + 2560);
}